// Round 11
// baseline (174.847 us; speedup 1.0000x reference)
//
#include <hip/hip_runtime.h>
#include <math.h>

#define T_SEQ 1024
#define BATCH 4
#define NTOK  4096      // BATCH * T_SEQ
#define DM    512
#define NH    8
#define DH    64

#define PI_F  3.14159274101257324f   // float(math.pi)
#define TPI_F 6.28318548202514648f   // float(2*math.pi)

typedef __attribute__((ext_vector_type(8))) short bf16x8;
typedef __attribute__((ext_vector_type(4))) float f32x4;

__device__ __forceinline__ ushort f2bf(float x) {   // RNE fp32 -> bf16
    uint u = __float_as_uint(x);
    return (ushort)((u + 0x7fffu + ((u >> 16) & 1u)) >> 16);
}

__device__ __forceinline__ float wrap_phi(float x) {
    // match jnp.mod(x + pi, 2pi) - pi  (divisor-sign semantics)
    float m = fmodf(x + PI_F, TPI_F);
    if (m < 0.0f) m += TPI_F;
    return m - PI_F;
}

// ---------------------------------------------------------------------------
// Kernel 1: fused prologue. Block ranges:
//   [0,2048):    p fp32 -> bf16
//   [2048,2304): weight transpose+cast (4 weights)
//   [2304,2560): packed RPE bin-index [B,T,T] u16 = (eb+16) | ((pb+16)<<5)
// ---------------------------------------------------------------------------
__global__ __launch_bounds__(256) void prep_kernel(
        const float* __restrict__ p, const float* __restrict__ pcoords,
        const float* __restrict__ w0, const float* __restrict__ w1,
        const float* __restrict__ w2, const float* __restrict__ w3,
        ushort* __restrict__ pb, ushort* __restrict__ oqkv,
        ushort* __restrict__ o3, ushort* __restrict__ bins) {
    int bid = blockIdx.x;
    int t   = threadIdx.x;

    if (bid < 2048) {                        // ---- p cast: 1024 floats/block
        int i = bid * 256 + t;
        float4 v = ((const float4*)p)[i];
        ushort4 o;
        o.x = f2bf(v.x); o.y = f2bf(v.y); o.z = f2bf(v.z); o.w = f2bf(v.w);
        ((ushort4*)pb)[i] = o;
    } else if (bid < 2304) {                 // ---- weight transpose 64x64 tile
        int id = bid - 2048;
        int z  = id >> 6, rem = id & 63;
        int n0 = (rem & 7) * 64, k0 = (rem >> 3) * 64;
        const float* W; ushort* O;
        switch (z) {
            case 0:  W = w0; O = oqkv; break;
            case 1:  W = w1; O = oqkv + (size_t)DM * DM; break;
            case 2:  W = w2; O = oqkv + (size_t)2 * DM * DM; break;
            default: W = w3; O = o3; break;
        }
        __shared__ ushort Ls[64][72];
#pragma unroll
        for (int i = 0; i < 4; ++i) {
            int kr = (t >> 4) + i * 16;
            float4 v = *(const float4*)(W + (size_t)(k0 + kr) * DM + n0 + (t & 15) * 4);
            Ls[(t & 15) * 4 + 0][kr] = f2bf(v.x);
            Ls[(t & 15) * 4 + 1][kr] = f2bf(v.y);
            Ls[(t & 15) * 4 + 2][kr] = f2bf(v.z);
            Ls[(t & 15) * 4 + 3][kr] = f2bf(v.w);
        }
        __syncthreads();
#pragma unroll
        for (int i = 0; i < 4; ++i) {
            int nl = (t >> 4) + i * 16;
            int k4 = (t & 15) * 4;
            ushort4 u;
            u.x = Ls[nl][k4 + 0]; u.y = Ls[nl][k4 + 1];
            u.z = Ls[nl][k4 + 2]; u.w = Ls[nl][k4 + 3];
            *(ushort4*)(O + (size_t)(n0 + nl) * DM + k0 + k4) = u;
        }
    } else {                                 // ---- bins (with in-block er)
        __shared__ float rng[4];
        __shared__ float er_s;
        {   // wave wb reduces batch wb's eta range via shfl butterfly
            int wb = t >> 6, l = t & 63;
            float mn = 3.0e38f, mx = -3.0e38f;
            for (int i = l; i < T_SEQ; i += 64) {
                float e = pcoords[(size_t)(wb * T_SEQ + i) * 2 + 0];
                mn = fminf(mn, e);
                mx = fmaxf(mx, e);
            }
#pragma unroll
            for (int off = 1; off < 64; off <<= 1) {
                mn = fminf(mn, __shfl_xor(mn, off));
                mx = fmaxf(mx, __shfl_xor(mx, off));
            }
            if (l == 0) rng[wb] = mx - mn;
            __syncthreads();
            if (t == 0)
                er_s = fmaxf(fmaxf(fmaxf(rng[0], rng[1]), fmaxf(rng[2], rng[3])), 1e-6f);
            __syncthreads();
        }
        const float er = er_s;
        int id = bid - 2304;
        int b  = id >> 6;
        int q  = (id & 63) * 16 + (t >> 4);
        int k0 = (t & 15) * 64;
        float2 qc = *(const float2*)(pcoords + (size_t)(b * T_SEQ + q) * 2);
        ushort* orow = bins + ((size_t)(b * T_SEQ + q)) * T_SEQ + k0;
        for (int j = 0; j < 64; j += 4) {
            ushort tmp[4];
#pragma unroll
            for (int jj = 0; jj < 4; ++jj) {
                float2 kc = *(const float2*)(pcoords + (size_t)(b * T_SEQ + k0 + j + jj) * 2);
                float re = qc.x - kc.x;
                float rp = wrap_phi(qc.y - kc.y);
                int eb = (int)(re / er * 16.0f);    // IEEE div; trunc toward 0
                int pbn = (int)(rp / PI_F * 16.0f);
                eb  = eb  < -16 ? -16 : (eb  > 15 ? 15 : eb);
                pbn = pbn < -16 ? -16 : (pbn > 15 ? 15 : pbn);
                tmp[jj] = (ushort)((eb + 16) | ((pbn + 16) << 5));   // 10-bit idx
            }
            ushort4 u; u.x = tmp[0]; u.y = tmp[1]; u.z = tmp[2]; u.w = tmp[3];
            *(ushort4*)&orow[j] = u;
        }
    }
}

// ---------------------------------------------------------------------------
// Kernel 2: fused QKV projection GEMM, BM=128 BN=64 BK=64, 2-phase dbuf.
// grid (24, 32); n0 range selects output:
//   [0,512):    q -> bf16 [m][n], scale 0.125 (folds 1/sqrt(dh))
//   [512,1024): k -> bf16 [m][n]
//   [1024,1536):v -> vbT [(b*8+h)*64+d][1024] bf16 (pre-transposed for PV)
// ---------------------------------------------------------------------------
__global__ __launch_bounds__(256) void gemm_qkv(
        const ushort* __restrict__ A, const ushort* __restrict__ Bt,
        const float* __restrict__ bq, const float* __restrict__ bk,
        const float* __restrict__ bv, ushort* __restrict__ qout,
        ushort* __restrict__ kout, ushort* __restrict__ vout) {
    // SMEM: As dbuf 2x16KB, Bs dbuf 2x8KB = 48KB; epilogue reuses As region.
    __shared__ __align__(16) ushort As[2][128 * 64];
    __shared__ __align__(16) ushort Bs[2][64 * 64];
    int t  = threadIdx.x;
    int w  = t >> 6, ln = t & 63;
    int wr = w >> 1, wc = w & 1;
    int n0 = blockIdx.x * 64;
    int m0 = blockIdx.y * 128;
    int row16 = ln & 15, kg = ln >> 4;

    f32x4 acc[4][2];
#pragma unroll
    for (int i = 0; i < 4; ++i)
#pragma unroll
        for (int j = 0; j < 2; ++j) acc[i][j] = (f32x4)0.0f;

    auto stage = [&](int buf, int kb) {
#pragma unroll
        for (int issue = 0; issue < 4; ++issue) {       // A: 1024 chunks
            int chunk = issue * 256 + w * 64 + ln;
            int r = chunk >> 3, s = chunk & 7;
            int gcol = kb + ((s ^ (r & 7)) * 8);
            const ushort* ga = A + (size_t)(m0 + r) * DM + gcol;
            __builtin_amdgcn_global_load_lds((const void*)ga,
                (void*)(&As[buf][(issue * 256 + w * 64) * 8]), 16, 0, 0);
        }
#pragma unroll
        for (int issue = 0; issue < 2; ++issue) {       // B: 512 chunks
            int chunk = issue * 256 + w * 64 + ln;
            int r = chunk >> 3, s = chunk & 7;
            int gcol = kb + ((s ^ (r & 7)) * 8);
            const ushort* gb = Bt + (size_t)(n0 + r) * DM + gcol;
            __builtin_amdgcn_global_load_lds((const void*)gb,
                (void*)(&Bs[buf][(issue * 256 + w * 64) * 8]), 16, 0, 0);
        }
    };

    stage(0, 0);
    __syncthreads();
    for (int ki = 0; ki < 8; ++ki) {
        int cur = ki & 1;
        if (ki < 7) stage(cur ^ 1, (ki + 1) * 64);
#pragma unroll
        for (int kk = 0; kk < 2; ++kk) {
            int swz = (kk * 32 + kg * 8) ^ ((row16 & 7) << 3);
            bf16x8 af[4], bfr[2];
#pragma unroll
            for (int f = 0; f < 4; ++f)
                af[f] = *(const bf16x8*)&As[cur][(64 * wr + f * 16 + row16) * 64 + swz];
#pragma unroll
            for (int f = 0; f < 2; ++f)
                bfr[f] = *(const bf16x8*)&Bs[cur][(32 * wc + f * 16 + row16) * 64 + swz];
            __builtin_amdgcn_s_setprio(1);
#pragma unroll
            for (int fr = 0; fr < 4; ++fr)
#pragma unroll
                for (int fc = 0; fc < 2; ++fc)
                    acc[fr][fc] = __builtin_amdgcn_mfma_f32_16x16x32_bf16(
                        af[fr], bfr[fc], acc[fr][fc], 0, 0, 0);
            __builtin_amdgcn_s_setprio(0);
        }
        __syncthreads();
    }

    // epilogue: C/D layout col=lane&15 (n), row=(lane>>4)*4+reg (m)
    int col = ln & 15, rbase = (ln >> 4) * 4;
    ushort* Cs = (ushort*)As;                // staging dead after final barrier

    if (n0 < 1024) {                         // q or k: bf16 [m][n-local]
        ushort* C = (n0 < 512) ? qout : kout;
        const float* bias = (n0 < 512) ? bq : bk;
        float scale = (n0 < 512) ? 0.125f : 1.0f;
        int nl0 = n0 & 511;
#pragma unroll
        for (int fc = 0; fc < 2; ++fc) {
            float bv_ = bias[nl0 + 32 * wc + fc * 16 + col];
#pragma unroll
            for (int fr = 0; fr < 4; ++fr)
#pragma unroll
                for (int reg = 0; reg < 4; ++reg)
                    Cs[(64 * wr + 16 * fr + rbase + reg) * 72 + 32 * wc + 16 * fc + col]
                        = f2bf((acc[fr][fc][reg] + bv_) * scale);
        }
        __syncthreads();
#pragma unroll
        for (int i = 0; i < 4; ++i) {        // 128 rows x 8 chunks
            int c = i * 256 + t;
            int row = c >> 3, s = c & 7;
            *(bf16x8*)&C[(size_t)(m0 + row) * DM + nl0 + s * 8]
                = *(const bf16x8*)&Cs[row * 72 + s * 8];
        }
    } else {                                 // v: transposed vbT layout
        int nl0 = n0 - 1024;                 // Cs[d][m_local], stride 136
#pragma unroll
        for (int fc = 0; fc < 2; ++fc) {
            float bv_ = bv[nl0 + 32 * wc + fc * 16 + col];
#pragma unroll
            for (int fr = 0; fr < 4; ++fr) {
                int mloc = 64 * wr + 16 * fr + rbase;
                int d    = 32 * wc + 16 * fc + col;
                Cs[d * 136 + mloc + 0] = f2bf(acc[fr][fc][0] + bv_);
                Cs[d * 136 + mloc + 1] = f2bf(acc[fr][fc][1] + bv_);
                Cs[d * 136 + mloc + 2] = f2bf(acc[fr][fc][2] + bv_);
                Cs[d * 136 + mloc + 3] = f2bf(acc[fr][fc][3] + bv_);
            }
        }
        __syncthreads();
#pragma unroll
        for (int i = 0; i < 4; ++i) {        // 64 d-rows x 16 chunks of 8
            int c = i * 256 + t;
            int row = c >> 4, s = c & 15;    // row = d, s*8 along m
            *(bf16x8*)&vout[((size_t)((m0 >> 10) * DM + nl0 + row)) * T_SEQ + (m0 & 1023) + s * 8]
                = *(const bf16x8*)&Cs[row * 136 + s * 8];
        }
    }
}

// ---------------------------------------------------------------------------
// Kernel 3: output projection GEMM, 64x64 tile, fp32 out (2-phase dbuf).
// ---------------------------------------------------------------------------
__global__ __launch_bounds__(256) void gemm_out(
        const ushort* __restrict__ A, const ushort* __restrict__ Bt,
        const float* __restrict__ bias, float* __restrict__ C) {
    __shared__ __align__(16) ushort SMEM[4][64 * 64];   // 32KB staging+epilogue
    int t  = threadIdx.x;
    int w  = t >> 6, ln = t & 63;
    int wr = w >> 1, wc = w & 1;
    int n0 = blockIdx.x * 64;
    int m0 = blockIdx.y * 64;
    int row16 = ln & 15, kg = ln >> 4;

    f32x4 acc[2][2];
#pragma unroll
    for (int i = 0; i < 2; ++i)
#pragma unroll
        for (int j = 0; j < 2; ++j) acc[i][j] = (f32x4)0.0f;

    auto stage = [&](int buf, int kb) {
#pragma unroll
        for (int issue = 0; issue < 2; ++issue) {
            int chunk = issue * 256 + w * 64 + ln;
            int r = chunk >> 3, s = chunk & 7;
            int gcol = kb + ((s ^ (r & 7)) * 8);
            const ushort* ga = A  + (size_t)(m0 + r) * DM + gcol;
            const ushort* gb = Bt + (size_t)(n0 + r) * DM + gcol;
            __builtin_amdgcn_global_load_lds((const void*)ga,
                (void*)(&SMEM[buf][(issue * 256 + w * 64) * 8]), 16, 0, 0);
            __builtin_amdgcn_global_load_lds((const void*)gb,
                (void*)(&SMEM[2 + buf][(issue * 256 + w * 64) * 8]), 16, 0, 0);
        }
    };

    stage(0, 0);
    __syncthreads();
    for (int ki = 0; ki < 8; ++ki) {
        int cur = ki & 1;
        if (ki < 7) stage(cur ^ 1, (ki + 1) * 64);
#pragma unroll
        for (int kk = 0; kk < 2; ++kk) {
            int swz = (kk * 32 + kg * 8) ^ ((row16 & 7) << 3);
            bf16x8 af[2], bfr[2];
#pragma unroll
            for (int f = 0; f < 2; ++f) {
                af[f]  = *(const bf16x8*)&SMEM[cur][(32 * wr + f * 16 + row16) * 64 + swz];
                bfr[f] = *(const bf16x8*)&SMEM[2 + cur][(32 * wc + f * 16 + row16) * 64 + swz];
            }
            __builtin_amdgcn_s_setprio(1);
#pragma unroll
            for (int fr = 0; fr < 2; ++fr)
#pragma unroll
                for (int fc = 0; fc < 2; ++fc)
                    acc[fr][fc] = __builtin_amdgcn_mfma_f32_16x16x32_bf16(
                        af[fr], bfr[fc], acc[fr][fc], 0, 0, 0);
            __builtin_amdgcn_s_setprio(0);
        }
        __syncthreads();
    }

    int col = ln & 15, rbase = (ln >> 4) * 4;
    float* Cf = (float*)SMEM;                // 64*68 float = 17.4KB ≤ 32KB
#pragma unroll
    for (int fc = 0; fc < 2; ++fc) {
        float bv = bias[n0 + 32 * wc + fc * 16 + col];
#pragma unroll
        for (int fr = 0; fr < 2; ++fr)
#pragma unroll
            for (int reg = 0; reg < 4; ++reg)
                Cf[(32 * wr + 16 * fr + rbase + reg) * 68 + 32 * wc + 16 * fc + col]
                    = acc[fr][fc][reg] + bv;
    }
    __syncthreads();
#pragma unroll
    for (int i = 0; i < 4; ++i) {
        int c = i * 256 + t;
        int row = c >> 4, s = c & 15;
        *(float4*)&C[(size_t)(m0 + row) * DM + n0 + s * 4] = *(float4*)&Cf[row * 68 + s * 4];
    }
}

// ---------------------------------------------------------------------------
// Kernel 4: MFMA flash attention, swapped-operand S^T = mfma(K, Q).
// K/Vt double-buffered via global_load_lds, prefetch at loop top, ONE
// barrier/tile. Q pre-scaled by 0.125. Lane-local softmax (q = lane&15).
// NEW: combined 1024-entry bias table (1 LDS read/elem), setprio on MFMA.
// ---------------------------------------------------------------------------
__global__ __launch_bounds__(256) void attn_mfma(
        const ushort* __restrict__ qb, const ushort* __restrict__ kb,
        const ushort* __restrict__ vt, const ushort* __restrict__ bins,
        const float* __restrict__ rpe, ushort* __restrict__ outb) {
    __shared__ ushort Ks[2][64 * 64];
    __shared__ ushort Vs[2][64 * 64];
    __shared__ ushort Ps[4][16 * 72];
    __shared__ float tbl2[1024];

    const int t  = threadIdx.x;
    const int w  = t >> 6, ln = t & 63;
    const int g  = ln >> 4, cq = ln & 15;
    const int qt = blockIdx.x, h = blockIdx.y, b = blockIdx.z;
    const int q0 = qt * 64;

    // combined bias table: tbl2[e | p<<5] = rpe[e][h] + rpe[32+p][h]
#pragma unroll
    for (int i = 0; i < 4; ++i) {
        int idx = t + 256 * i;
        tbl2[idx] = rpe[(idx & 31) * NH + h] + rpe[(32 + (idx >> 5)) * NH + h];
    }

    bf16x8 qf[2];
    {
        const ushort* qrow = qb + ((size_t)(b * T_SEQ + q0 + w * 16 + cq)) * DM + h * DH + g * 8;
        qf[0] = *(const bf16x8*)(qrow);
        qf[1] = *(const bf16x8*)(qrow + 32);
    }

    f32x4 oacc[4];
#pragma unroll
    for (int mb = 0; mb < 4; ++mb) oacc[mb] = (f32x4)0.0f;
    float m_run = -3.0e38f, l_run = 0.0f;

    const ushort* brow0 = bins + ((size_t)(b * T_SEQ + q0 + w * 16 + cq)) * T_SEQ;

    auto stage = [&](int buf, int kt2) {
        int k0s = kt2 * 64;
#pragma unroll
        for (int i = 0; i < 2; ++i) {
            int c = i * 256 + t;
            int r = c >> 3, s = c & 7;
            int cc = (s ^ (r & 7)) * 8;                 // pre-swizzled source col
            const ushort* gk = kb + ((size_t)(b * T_SEQ + k0s + r)) * DM + h * DH + cc;
            const ushort* gv = vt + ((size_t)((b * NH + h) * DH + r)) * T_SEQ + k0s + cc;
            __builtin_amdgcn_global_load_lds((const void*)gk,
                (void*)&Ks[buf][(i * 256 + w * 64) * 8], 16, 0, 0);
            __builtin_amdgcn_global_load_lds((const void*)gv,
                (void*)&Vs[buf][(i * 256 + w * 64) * 8], 16, 0, 0);
        }
    };

    stage(0, 0);
    __syncthreads();   // tile 0 staged + tbl2 visible

    for (int kt = 0; kt < 16; ++kt) {
        int cur = kt & 1;
        if (kt < 15) stage(cur ^ 1, kt + 1);   // async prefetch into alt buffer
        const ushort* K = Ks[cur];
        const ushort* V = Vs[cur];

        f32x4 sacc[4];
#pragma unroll
        for (int kvb = 0; kvb < 4; ++kvb) sacc[kvb] = (f32x4)0.0f;
        __builtin_amdgcn_s_setprio(1);
#pragma unroll
        for (int kc = 0; kc < 2; ++kc)
#pragma unroll
            for (int kvb = 0; kvb < 4; ++kvb) {
                bf16x8 kf = *(const bf16x8*)
                    &K[(kvb * 16 + cq) * 64 + (((g + 4 * kc) ^ (cq & 7)) * 8)];
                sacc[kvb] = __builtin_amdgcn_mfma_f32_16x16x32_bf16(
                    kf, qf[kc], sacc[kvb], 0, 0, 0);
            }
        __builtin_amdgcn_s_setprio(0);

        const ushort* brow = brow0 + kt * 64;
        float sv[16];
        float pm = -3.0e38f;
#pragma unroll
        for (int kvb = 0; kvb < 4; ++kvb) {
            ushort4 bi = *(const ushort4*)&brow[kvb * 16 + g * 4];
            ushort bb[4] = {bi.x, bi.y, bi.z, bi.w};
#pragma unroll
            for (int r = 0; r < 4; ++r) {
                float s = sacc[kvb][r] + tbl2[bb[r]];
                sv[kvb * 4 + r] = s;
                pm = fmaxf(pm, s);
            }
        }
        pm = fmaxf(pm, __shfl_xor(pm, 16));
        pm = fmaxf(pm, __shfl_xor(pm, 32));
        float mnew  = fmaxf(m_run, pm);
        float alpha = __expf(m_run - mnew);
        float psum  = 0.0f;
        ushort pk[16];
#pragma unroll
        for (int i = 0; i < 16; ++i) {
            float p = __expf(sv[i] - mnew);
            psum += p;
            pk[i] = f2bf(p);
        }
        psum += __shfl_xor(psum, 16);
        psum += __shfl_xor(psum, 32);
        l_run = l_run * alpha + psum;
        m_run = mnew;
#pragma unroll
        for (int mb = 0; mb < 4; ++mb) oacc[mb] *= alpha;

        ushort* Pw = &Ps[w][0];
#pragma unroll
        for (int kvb = 0; kvb < 4; ++kvb) {
            ushort4 u;
            u.x = pk[kvb * 4 + 0]; u.y = pk[kvb * 4 + 1];
            u.z = pk[kvb * 4 + 2]; u.w = pk[kvb * 4 + 3];
            *(ushort4*)&Pw[cq * 72 + kvb * 16 + g * 4] = u;
        }
        asm volatile("s_waitcnt lgkmcnt(0)" ::: "memory");
        __builtin_amdgcn_sched_barrier(0);

        __builtin_amdgcn_s_setprio(1);
#pragma unroll
        for (int kc = 0; kc < 2; ++kc) {
            bf16x8 pf = *(const bf16x8*)&Pw[cq * 72 + kc * 32 + g * 8];
#pragma unroll
            for (int mb = 0; mb < 4; ++mb) {
                bf16x8 vf = *(const bf16x8*)
                    &V[(mb * 16 + cq) * 64 + (((g + 4 * kc) ^ (cq & 7)) * 8)];
                oacc[mb] = __builtin_amdgcn_mfma_f32_16x16x32_bf16(
                    vf, pf, oacc[mb], 0, 0, 0);
            }
        }
        __builtin_amdgcn_s_setprio(0);
        __syncthreads();   // drains prefetch + joins waves before buffer reuse
    }

    float inv = 1.0f / l_run;
    ushort* Ow = &Ps[w][0];
#pragma unroll
    for (int mb = 0; mb < 4; ++mb) {
        ushort4 u;
        u.x = f2bf(oacc[mb][0] * inv);
        u.y = f2bf(oacc[mb][1] * inv);
        u.z = f2bf(oacc[mb][2] * inv);
        u.w = f2bf(oacc[mb][3] * inv);
        *(ushort4*)&Ow[cq * 72 + mb * 16 + g * 4] = u;
    }
    asm volatile("s_waitcnt lgkmcnt(0)" ::: "memory");
    __builtin_amdgcn_sched_barrier(0);
#pragma unroll
    for (int i = 0; i < 2; ++i) {
        int c = i * 64 + ln;
        int row = c >> 3, s = c & 7;
        bf16x8 val = *(const bf16x8*)&Ow[row * 72 + s * 8];
        *(bf16x8*)&outb[((size_t)(b * T_SEQ + q0 + w * 16 + row)) * DM + h * DH + s * 8] = val;
    }
}

// ---------------------------------------------------------------------------
extern "C" void kernel_launch(void* const* d_in, const int* in_sizes, int n_in,
                              void* d_out, int out_size, void* d_ws, size_t ws_size,
                              hipStream_t stream) {
    const float* p       = (const float*)d_in[0];
    const float* pcoords = (const float*)d_in[1];
    const float* rpe     = (const float*)d_in[2];
    const float* wq_w    = (const float*)d_in[3];
    const float* wq_b    = (const float*)d_in[4];
    const float* wk_w    = (const float*)d_in[5];
    const float* wk_b    = (const float*)d_in[6];
    const float* wv_w    = (const float*)d_in[7];
    const float* wv_b    = (const float*)d_in[8];
    const float* wo_w    = (const float*)d_in[9];
    const float* wo_b    = (const float*)d_in[10];
    float* out = (float*)d_out;

    const size_t NE = (size_t)NTOK * DM;      // 2M elems
    ushort* pb    = (ushort*)d_ws;            // bf16 p            [4096][512]
    ushort* qb16  = pb + NE;                  // bf16 q (x0.125)   [4096][512]
    ushort* kb16  = qb16 + NE;                // bf16 k            [4096][512]
    ushort* vbT   = kb16 + NE;                // bf16 v^T          [(b*8+h)*64+d][1024]
    ushort* ab    = vbT + NE;                 // bf16 attn out     [4096][512]
    ushort* wtQKV = ab + NE;                  // bf16 W^T concat   [1536][512]
    ushort* wt3   = wtQKV + (size_t)3 * DM * DM;
    ushort* bins  = wt3 + (size_t)DM * DM;    // u16 packed idx    [4][1024][1024]

    prep_kernel<<<2560, 256, 0, stream>>>(
        p, pcoords, wq_w, wk_w, wv_w, wo_w, pb, wtQKV, wt3, bins);

    gemm_qkv<<<dim3(24, NTOK / 128), 256, 0, stream>>>(
        pb, wtQKV, wq_b, wk_b, wv_b, qb16, kb16, vbT);

    attn_mfma<<<dim3(16, NH, BATCH), 256, 0, stream>>>(
        qb16, kb16, vbT, bins, rpe, ab);

    gemm_out<<<dim3(8, NTOK / 64), 256, 0, stream>>>(ab, wt3, wo_b, out);
}

// Round 13
// 151.911 us; speedup vs baseline: 1.1510x; 1.1510x over previous
//
#include <hip/hip_runtime.h>
#include <math.h>

#define T_SEQ 1024
#define BATCH 4
#define NTOK  4096      // BATCH * T_SEQ
#define DM    512
#define NH    8
#define DH    64

#define PI_F  3.14159274101257324f   // float(math.pi)
#define TPI_F 6.28318548202514648f   // float(2*math.pi)

typedef __attribute__((ext_vector_type(8))) short bf16x8;
typedef __attribute__((ext_vector_type(8))) ushort u16x8;
typedef __attribute__((ext_vector_type(4))) float f32x4;

__device__ __forceinline__ ushort f2bf(float x) {   // RNE fp32 -> bf16
    uint u = __float_as_uint(x);
    return (ushort)((u + 0x7fffu + ((u >> 16) & 1u)) >> 16);
}

__device__ __forceinline__ float wrap_phi(float x) {
    // match jnp.mod(x + pi, 2pi) - pi  (divisor-sign semantics)
    float m = fmodf(x + PI_F, TPI_F);
    if (m < 0.0f) m += TPI_F;
    return m - PI_F;
}

// ---------------------------------------------------------------------------
// Kernel 1: fused prologue. Block ranges (bins FIRST — it's the long pole):
//   [0,1024):    packed RPE bin-index, 4 q-rows/block, k-coords staged in LDS
//   [1024,3072): p fp32 -> bf16
//   [3072,3328): weight transpose+cast (4 weights)
// ---------------------------------------------------------------------------
__global__ __launch_bounds__(256) void prep_kernel(
        const float* __restrict__ p, const float* __restrict__ pcoords,
        const float* __restrict__ w0, const float* __restrict__ w1,
        const float* __restrict__ w2, const float* __restrict__ w3,
        ushort* __restrict__ pb, ushort* __restrict__ oqkv,
        ushort* __restrict__ o3, ushort* __restrict__ bins) {
    int bid = blockIdx.x;
    int t   = threadIdx.x;

    if (bid < 1024) {                        // ---- bins: 4 q-rows per block
        __shared__ float2 kcs[1024];         // batch's coords (8KB)
        __shared__ float rng[4];
        __shared__ float er_s;
        int b  = bid >> 8;                   // 0..3
        int q0 = (bid & 255) * 4;            // 0..1020
        {   // wave wb reduces batch wb's eta range via shfl butterfly
            int wb = t >> 6, l = t & 63;
            float mn = 3.0e38f, mx = -3.0e38f;
            for (int i = l; i < T_SEQ; i += 64) {
                float e = pcoords[(size_t)(wb * T_SEQ + i) * 2 + 0];
                mn = fminf(mn, e);
                mx = fmaxf(mx, e);
            }
#pragma unroll
            for (int off = 1; off < 64; off <<= 1) {
                mn = fminf(mn, __shfl_xor(mn, off));
                mx = fmaxf(mx, __shfl_xor(mx, off));
            }
            if (l == 0) rng[wb] = mx - mn;
        }
        // stage batch b's 1024 coords: thread t loads 4 consecutive float2
#pragma unroll
        for (int i = 0; i < 2; ++i) {
            float4 v = ((const float4*)pcoords)[(size_t)(b * T_SEQ) / 2 + t * 2 + i];
            kcs[t * 4 + i * 2 + 0] = make_float2(v.x, v.y);
            kcs[t * 4 + i * 2 + 1] = make_float2(v.z, v.w);
        }
        __syncthreads();
        if (t == 0)
            er_s = fmaxf(fmaxf(fmaxf(rng[0], rng[1]), fmaxf(rng[2], rng[3])), 1e-6f);
        __syncthreads();
        const float er = er_s;

        int qi   = t >> 6;                   // 0..3: q-row within group
        int lane = t & 63;                   // 16 k's per lane
        int q    = q0 + qi;
        float2 qc = kcs[q];
        ushort tmp[16];
#pragma unroll
        for (int j = 0; j < 16; ++j) {
            float2 kc = kcs[lane * 16 + j];
            float re = qc.x - kc.x;
            float rp = wrap_phi(qc.y - kc.y);
            int eb  = (int)(re / er * 16.0f);    // IEEE div; trunc toward 0
            int pbn = (int)(rp / PI_F * 16.0f);
            eb  = eb  < -16 ? -16 : (eb  > 15 ? 15 : eb);
            pbn = pbn < -16 ? -16 : (pbn > 15 ? 15 : pbn);
            tmp[j] = (ushort)((eb + 16) | ((pbn + 16) << 5));   // 10-bit idx
        }
        ushort* orow = bins + ((size_t)(b * T_SEQ + q)) * T_SEQ + lane * 16;
        u16x8 v0, v1;
#pragma unroll
        for (int j = 0; j < 8; ++j) { v0[j] = tmp[j]; v1[j] = tmp[8 + j]; }
        *(u16x8*)&orow[0] = v0;
        *(u16x8*)&orow[8] = v1;
    } else if (bid < 3072) {                 // ---- p cast: 1024 floats/block
        int i = (bid - 1024) * 256 + t;
        float4 v = ((const float4*)p)[i];
        ushort4 o;
        o.x = f2bf(v.x); o.y = f2bf(v.y); o.z = f2bf(v.z); o.w = f2bf(v.w);
        ((ushort4*)pb)[i] = o;
    } else {                                 // ---- weight transpose 64x64 tile
        int id = bid - 3072;
        int z  = id >> 6, rem = id & 63;
        int n0 = (rem & 7) * 64, k0 = (rem >> 3) * 64;
        const float* W; ushort* O;
        switch (z) {
            case 0:  W = w0; O = oqkv; break;
            case 1:  W = w1; O = oqkv + (size_t)DM * DM; break;
            case 2:  W = w2; O = oqkv + (size_t)2 * DM * DM; break;
            default: W = w3; O = o3; break;
        }
        __shared__ ushort Ls[64][72];
#pragma unroll
        for (int i = 0; i < 4; ++i) {
            int kr = (t >> 4) + i * 16;
            float4 v = *(const float4*)(W + (size_t)(k0 + kr) * DM + n0 + (t & 15) * 4);
            Ls[(t & 15) * 4 + 0][kr] = f2bf(v.x);
            Ls[(t & 15) * 4 + 1][kr] = f2bf(v.y);
            Ls[(t & 15) * 4 + 2][kr] = f2bf(v.z);
            Ls[(t & 15) * 4 + 3][kr] = f2bf(v.w);
        }
        __syncthreads();
#pragma unroll
        for (int i = 0; i < 4; ++i) {
            int nl = (t >> 4) + i * 16;
            int k4 = (t & 15) * 4;
            ushort4 u;
            u.x = Ls[nl][k4 + 0]; u.y = Ls[nl][k4 + 1];
            u.z = Ls[nl][k4 + 2]; u.w = Ls[nl][k4 + 3];
            *(ushort4*)(O + (size_t)(n0 + nl) * DM + k0 + k4) = u;
        }
    }
}

// ---------------------------------------------------------------------------
// Kernel 2: fused QKV projection GEMM, BM=128 BN=64 BK=64, 2-phase dbuf.
// grid (24, 32); n0 range selects output:
//   [0,512):    q -> bf16 [m][n], scale 0.125 (folds 1/sqrt(dh))
//   [512,1024): k -> bf16 [m][n]
//   [1024,1536):v -> vbT [(b*8+h)*64+d][1024] bf16 (pre-transposed for PV)
// ---------------------------------------------------------------------------
__global__ __launch_bounds__(256) void gemm_qkv(
        const ushort* __restrict__ A, const ushort* __restrict__ Bt,
        const float* __restrict__ bq, const float* __restrict__ bk,
        const float* __restrict__ bv, ushort* __restrict__ qout,
        ushort* __restrict__ kout, ushort* __restrict__ vout) {
    // SMEM: As dbuf 2x16KB, Bs dbuf 2x8KB = 48KB; epilogue reuses As region.
    __shared__ __align__(16) ushort As[2][128 * 64];
    __shared__ __align__(16) ushort Bs[2][64 * 64];
    int t  = threadIdx.x;
    int w  = t >> 6, ln = t & 63;
    int wr = w >> 1, wc = w & 1;
    int n0 = blockIdx.x * 64;
    int m0 = blockIdx.y * 128;
    int row16 = ln & 15, kg = ln >> 4;

    f32x4 acc[4][2];
#pragma unroll
    for (int i = 0; i < 4; ++i)
#pragma unroll
        for (int j = 0; j < 2; ++j) acc[i][j] = (f32x4)0.0f;

    auto stage = [&](int buf, int kb) {
#pragma unroll
        for (int issue = 0; issue < 4; ++issue) {       // A: 1024 chunks
            int chunk = issue * 256 + w * 64 + ln;
            int r = chunk >> 3, s = chunk & 7;
            int gcol = kb + ((s ^ (r & 7)) * 8);
            const ushort* ga = A + (size_t)(m0 + r) * DM + gcol;
            __builtin_amdgcn_global_load_lds((const void*)ga,
                (void*)(&As[buf][(issue * 256 + w * 64) * 8]), 16, 0, 0);
        }
#pragma unroll
        for (int issue = 0; issue < 2; ++issue) {       // B: 512 chunks
            int chunk = issue * 256 + w * 64 + ln;
            int r = chunk >> 3, s = chunk & 7;
            int gcol = kb + ((s ^ (r & 7)) * 8);
            const ushort* gb = Bt + (size_t)(n0 + r) * DM + gcol;
            __builtin_amdgcn_global_load_lds((const void*)gb,
                (void*)(&Bs[buf][(issue * 256 + w * 64) * 8]), 16, 0, 0);
        }
    };

    stage(0, 0);
    __syncthreads();
    for (int ki = 0; ki < 8; ++ki) {
        int cur = ki & 1;
        if (ki < 7) stage(cur ^ 1, (ki + 1) * 64);
#pragma unroll
        for (int kk = 0; kk < 2; ++kk) {
            int swz = (kk * 32 + kg * 8) ^ ((row16 & 7) << 3);
            bf16x8 af[4], bfr[2];
#pragma unroll
            for (int f = 0; f < 4; ++f)
                af[f] = *(const bf16x8*)&As[cur][(64 * wr + f * 16 + row16) * 64 + swz];
#pragma unroll
            for (int f = 0; f < 2; ++f)
                bfr[f] = *(const bf16x8*)&Bs[cur][(32 * wc + f * 16 + row16) * 64 + swz];
            __builtin_amdgcn_s_setprio(1);
#pragma unroll
            for (int fr = 0; fr < 4; ++fr)
#pragma unroll
                for (int fc = 0; fc < 2; ++fc)
                    acc[fr][fc] = __builtin_amdgcn_mfma_f32_16x16x32_bf16(
                        af[fr], bfr[fc], acc[fr][fc], 0, 0, 0);
            __builtin_amdgcn_s_setprio(0);
        }
        __syncthreads();
    }

    // epilogue: C/D layout col=lane&15 (n), row=(lane>>4)*4+reg (m)
    int col = ln & 15, rbase = (ln >> 4) * 4;
    ushort* Cs = (ushort*)As;                // staging dead after final barrier

    if (n0 < 1024) {                         // q or k: bf16 [m][n-local]
        ushort* C = (n0 < 512) ? qout : kout;
        const float* bias = (n0 < 512) ? bq : bk;
        float scale = (n0 < 512) ? 0.125f : 1.0f;
        int nl0 = n0 & 511;
#pragma unroll
        for (int fc = 0; fc < 2; ++fc) {
            float bv_ = bias[nl0 + 32 * wc + fc * 16 + col];
#pragma unroll
            for (int fr = 0; fr < 4; ++fr)
#pragma unroll
                for (int reg = 0; reg < 4; ++reg)
                    Cs[(64 * wr + 16 * fr + rbase + reg) * 72 + 32 * wc + 16 * fc + col]
                        = f2bf((acc[fr][fc][reg] + bv_) * scale);
        }
        __syncthreads();
#pragma unroll
        for (int i = 0; i < 4; ++i) {        // 128 rows x 8 chunks
            int c = i * 256 + t;
            int row = c >> 3, s = c & 7;
            *(bf16x8*)&C[(size_t)(m0 + row) * DM + nl0 + s * 8]
                = *(const bf16x8*)&Cs[row * 72 + s * 8];
        }
    } else {                                 // v: transposed vbT layout
        int nl0 = n0 - 1024;                 // Cs[d][m_local], stride 136
#pragma unroll
        for (int fc = 0; fc < 2; ++fc) {
            float bv_ = bv[nl0 + 32 * wc + fc * 16 + col];
#pragma unroll
            for (int fr = 0; fr < 4; ++fr) {
                int mloc = 64 * wr + 16 * fr + rbase;
                int d    = 32 * wc + 16 * fc + col;
                Cs[d * 136 + mloc + 0] = f2bf(acc[fr][fc][0] + bv_);
                Cs[d * 136 + mloc + 1] = f2bf(acc[fr][fc][1] + bv_);
                Cs[d * 136 + mloc + 2] = f2bf(acc[fr][fc][2] + bv_);
                Cs[d * 136 + mloc + 3] = f2bf(acc[fr][fc][3] + bv_);
            }
        }
        __syncthreads();
#pragma unroll
        for (int i = 0; i < 4; ++i) {        // 64 d-rows x 16 chunks of 8
            int c = i * 256 + t;
            int row = c >> 4, s = c & 15;    // row = d, s*8 along m
            *(bf16x8*)&vout[((size_t)((m0 >> 10) * DM + nl0 + row)) * T_SEQ + (m0 & 1023) + s * 8]
                = *(const bf16x8*)&Cs[row * 136 + s * 8];
        }
    }
}

// ---------------------------------------------------------------------------
// Kernel 3: output projection GEMM, 64x64 tile, fp32 out (2-phase dbuf).
// ---------------------------------------------------------------------------
__global__ __launch_bounds__(256) void gemm_out(
        const ushort* __restrict__ A, const ushort* __restrict__ Bt,
        const float* __restrict__ bias, float* __restrict__ C) {
    __shared__ __align__(16) ushort SMEM[4][64 * 64];   // 32KB staging+epilogue
    int t  = threadIdx.x;
    int w  = t >> 6, ln = t & 63;
    int wr = w >> 1, wc = w & 1;
    int n0 = blockIdx.x * 64;
    int m0 = blockIdx.y * 64;
    int row16 = ln & 15, kg = ln >> 4;

    f32x4 acc[2][2];
#pragma unroll
    for (int i = 0; i < 2; ++i)
#pragma unroll
        for (int j = 0; j < 2; ++j) acc[i][j] = (f32x4)0.0f;

    auto stage = [&](int buf, int kb) {
#pragma unroll
        for (int issue = 0; issue < 2; ++issue) {
            int chunk = issue * 256 + w * 64 + ln;
            int r = chunk >> 3, s = chunk & 7;
            int gcol = kb + ((s ^ (r & 7)) * 8);
            const ushort* ga = A  + (size_t)(m0 + r) * DM + gcol;
            const ushort* gb = Bt + (size_t)(n0 + r) * DM + gcol;
            __builtin_amdgcn_global_load_lds((const void*)ga,
                (void*)(&SMEM[buf][(issue * 256 + w * 64) * 8]), 16, 0, 0);
            __builtin_amdgcn_global_load_lds((const void*)gb,
                (void*)(&SMEM[2 + buf][(issue * 256 + w * 64) * 8]), 16, 0, 0);
        }
    };

    stage(0, 0);
    __syncthreads();
    for (int ki = 0; ki < 8; ++ki) {
        int cur = ki & 1;
        if (ki < 7) stage(cur ^ 1, (ki + 1) * 64);
#pragma unroll
        for (int kk = 0; kk < 2; ++kk) {
            int swz = (kk * 32 + kg * 8) ^ ((row16 & 7) << 3);
            bf16x8 af[2], bfr[2];
#pragma unroll
            for (int f = 0; f < 2; ++f) {
                af[f]  = *(const bf16x8*)&SMEM[cur][(32 * wr + f * 16 + row16) * 64 + swz];
                bfr[f] = *(const bf16x8*)&SMEM[2 + cur][(32 * wc + f * 16 + row16) * 64 + swz];
            }
            __builtin_amdgcn_s_setprio(1);
#pragma unroll
            for (int fr = 0; fr < 2; ++fr)
#pragma unroll
                for (int fc = 0; fc < 2; ++fc)
                    acc[fr][fc] = __builtin_amdgcn_mfma_f32_16x16x32_bf16(
                        af[fr], bfr[fc], acc[fr][fc], 0, 0, 0);
            __builtin_amdgcn_s_setprio(0);
        }
        __syncthreads();
    }

    int col = ln & 15, rbase = (ln >> 4) * 4;
    float* Cf = (float*)SMEM;                // 64*68 float = 17.4KB ≤ 32KB
#pragma unroll
    for (int fc = 0; fc < 2; ++fc) {
        float bv = bias[n0 + 32 * wc + fc * 16 + col];
#pragma unroll
        for (int fr = 0; fr < 2; ++fr)
#pragma unroll
            for (int reg = 0; reg < 4; ++reg)
                Cf[(32 * wr + 16 * fr + rbase + reg) * 68 + 32 * wc + 16 * fc + col]
                    = acc[fr][fc][reg] + bv;
    }
    __syncthreads();
#pragma unroll
    for (int i = 0; i < 4; ++i) {
        int c = i * 256 + t;
        int row = c >> 4, s = c & 15;
        *(float4*)&C[(size_t)(m0 + row) * DM + n0 + s * 4] = *(float4*)&Cf[row * 68 + s * 4];
    }
}

// ---------------------------------------------------------------------------
// Kernel 4: MFMA flash attention, swapped-operand S^T = mfma(K, Q).
// K/Vt double-buffered via global_load_lds, prefetch at loop top, ONE
// barrier/tile. Q pre-scaled by 0.125. Lane-local softmax (q = lane&15).
// Combined 1024-entry bias table (1 LDS read/elem), setprio on MFMA.
// ---------------------------------------------------------------------------
__global__ __launch_bounds__(256) void attn_mfma(
        const ushort* __restrict__ qb, const ushort* __restrict__ kb,
        const ushort* __restrict__ vt, const ushort* __restrict__ bins,
        const float* __restrict__ rpe, ushort* __restrict__ outb) {
    __shared__ ushort Ks[2][64 * 64];
    __shared__ ushort Vs[2][64 * 64];
    __shared__ ushort Ps[4][16 * 72];
    __shared__ float tbl2[1024];

    const int t  = threadIdx.x;
    const int w  = t >> 6, ln = t & 63;
    const int g  = ln >> 4, cq = ln & 15;
    const int qt = blockIdx.x, h = blockIdx.y, b = blockIdx.z;
    const int q0 = qt * 64;

    // combined bias table: tbl2[e | p<<5] = rpe[e][h] + rpe[32+p][h]
#pragma unroll
    for (int i = 0; i < 4; ++i) {
        int idx = t + 256 * i;
        tbl2[idx] = rpe[(idx & 31) * NH + h] + rpe[(32 + (idx >> 5)) * NH + h];
    }

    bf16x8 qf[2];
    {
        const ushort* qrow = qb + ((size_t)(b * T_SEQ + q0 + w * 16 + cq)) * DM + h * DH + g * 8;
        qf[0] = *(const bf16x8*)(qrow);
        qf[1] = *(const bf16x8*)(qrow + 32);
    }

    f32x4 oacc[4];
#pragma unroll
    for (int mb = 0; mb < 4; ++mb) oacc[mb] = (f32x4)0.0f;
    float m_run = -3.0e38f, l_run = 0.0f;

    const ushort* brow0 = bins + ((size_t)(b * T_SEQ + q0 + w * 16 + cq)) * T_SEQ;

    auto stage = [&](int buf, int kt2) {
        int k0s = kt2 * 64;
#pragma unroll
        for (int i = 0; i < 2; ++i) {
            int c = i * 256 + t;
            int r = c >> 3, s = c & 7;
            int cc = (s ^ (r & 7)) * 8;                 // pre-swizzled source col
            const ushort* gk = kb + ((size_t)(b * T_SEQ + k0s + r)) * DM + h * DH + cc;
            const ushort* gv = vt + ((size_t)((b * NH + h) * DH + r)) * T_SEQ + k0s + cc;
            __builtin_amdgcn_global_load_lds((const void*)gk,
                (void*)&Ks[buf][(i * 256 + w * 64) * 8], 16, 0, 0);
            __builtin_amdgcn_global_load_lds((const void*)gv,
                (void*)&Vs[buf][(i * 256 + w * 64) * 8], 16, 0, 0);
        }
    };

    stage(0, 0);
    __syncthreads();   // tile 0 staged + tbl2 visible

    for (int kt = 0; kt < 16; ++kt) {
        int cur = kt & 1;
        if (kt < 15) stage(cur ^ 1, kt + 1);   // async prefetch into alt buffer
        const ushort* K = Ks[cur];
        const ushort* V = Vs[cur];

        f32x4 sacc[4];
#pragma unroll
        for (int kvb = 0; kvb < 4; ++kvb) sacc[kvb] = (f32x4)0.0f;
        __builtin_amdgcn_s_setprio(1);
#pragma unroll
        for (int kc = 0; kc < 2; ++kc)
#pragma unroll
            for (int kvb = 0; kvb < 4; ++kvb) {
                bf16x8 kf = *(const bf16x8*)
                    &K[(kvb * 16 + cq) * 64 + (((g + 4 * kc) ^ (cq & 7)) * 8)];
                sacc[kvb] = __builtin_amdgcn_mfma_f32_16x16x32_bf16(
                    kf, qf[kc], sacc[kvb], 0, 0, 0);
            }
        __builtin_amdgcn_s_setprio(0);

        const ushort* brow = brow0 + kt * 64;
        float sv[16];
        float pm = -3.0e38f;
#pragma unroll
        for (int kvb = 0; kvb < 4; ++kvb) {
            ushort4 bi = *(const ushort4*)&brow[kvb * 16 + g * 4];
            ushort bb[4] = {bi.x, bi.y, bi.z, bi.w};
#pragma unroll
            for (int r = 0; r < 4; ++r) {
                float s = sacc[kvb][r] + tbl2[bb[r]];
                sv[kvb * 4 + r] = s;
                pm = fmaxf(pm, s);
            }
        }
        pm = fmaxf(pm, __shfl_xor(pm, 16));
        pm = fmaxf(pm, __shfl_xor(pm, 32));
        float mnew  = fmaxf(m_run, pm);
        float alpha = __expf(m_run - mnew);
        float psum  = 0.0f;
        ushort pk[16];
#pragma unroll
        for (int i = 0; i < 16; ++i) {
            float p = __expf(sv[i] - mnew);
            psum += p;
            pk[i] = f2bf(p);
        }
        psum += __shfl_xor(psum, 16);
        psum += __shfl_xor(psum, 32);
        l_run = l_run * alpha + psum;
        m_run = mnew;
#pragma unroll
        for (int mb = 0; mb < 4; ++mb) oacc[mb] *= alpha;

        ushort* Pw = &Ps[w][0];
#pragma unroll
        for (int kvb = 0; kvb < 4; ++kvb) {
            ushort4 u;
            u.x = pk[kvb * 4 + 0]; u.y = pk[kvb * 4 + 1];
            u.z = pk[kvb * 4 + 2]; u.w = pk[kvb * 4 + 3];
            *(ushort4*)&Pw[cq * 72 + kvb * 16 + g * 4] = u;
        }
        asm volatile("s_waitcnt lgkmcnt(0)" ::: "memory");
        __builtin_amdgcn_sched_barrier(0);

        __builtin_amdgcn_s_setprio(1);
#pragma unroll
        for (int kc = 0; kc < 2; ++kc) {
            bf16x8 pf = *(const bf16x8*)&Pw[cq * 72 + kc * 32 + g * 8];
#pragma unroll
            for (int mb = 0; mb < 4; ++mb) {
                bf16x8 vf = *(const bf16x8*)
                    &V[(mb * 16 + cq) * 64 + (((g + 4 * kc) ^ (cq & 7)) * 8)];
                oacc[mb] = __builtin_amdgcn_mfma_f32_16x16x32_bf16(
                    vf, pf, oacc[mb], 0, 0, 0);
            }
        }
        __builtin_amdgcn_s_setprio(0);
        __syncthreads();   // drains prefetch + joins waves before buffer reuse
    }

    float inv = 1.0f / l_run;
    ushort* Ow = &Ps[w][0];
#pragma unroll
    for (int mb = 0; mb < 4; ++mb) {
        ushort4 u;
        u.x = f2bf(oacc[mb][0] * inv);
        u.y = f2bf(oacc[mb][1] * inv);
        u.z = f2bf(oacc[mb][2] * inv);
        u.w = f2bf(oacc[mb][3] * inv);
        *(ushort4*)&Ow[cq * 72 + mb * 16 + g * 4] = u;
    }
    asm volatile("s_waitcnt lgkmcnt(0)" ::: "memory");
    __builtin_amdgcn_sched_barrier(0);
#pragma unroll
    for (int i = 0; i < 2; ++i) {
        int c = i * 64 + ln;
        int row = c >> 3, s = c & 7;
        bf16x8 val = *(const bf16x8*)&Ow[row * 72 + s * 8];
        *(bf16x8*)&outb[((size_t)(b * T_SEQ + q0 + w * 16 + row)) * DM + h * DH + s * 8] = val;
    }
}

// ---------------------------------------------------------------------------
extern "C" void kernel_launch(void* const* d_in, const int* in_sizes, int n_in,
                              void* d_out, int out_size, void* d_ws, size_t ws_size,
                              hipStream_t stream) {
    const float* p       = (const float*)d_in[0];
    const float* pcoords = (const float*)d_in[1];
    const float* rpe     = (const float*)d_in[2];
    const float* wq_w    = (const float*)d_in[3];
    const float* wq_b    = (const float*)d_in[4];
    const float* wk_w    = (const float*)d_in[5];
    const float* wk_b    = (const float*)d_in[6];
    const float* wv_w    = (const float*)d_in[7];
    const float* wv_b    = (const float*)d_in[8];
    const float* wo_w    = (const float*)d_in[9];
    const float* wo_b    = (const float*)d_in[10];
    float* out = (float*)d_out;

    const size_t NE = (size_t)NTOK * DM;      // 2M elems
    ushort* pb    = (ushort*)d_ws;            // bf16 p            [4096][512]
    ushort* qb16  = pb + NE;                  // bf16 q (x0.125)   [4096][512]
    ushort* kb16  = qb16 + NE;                // bf16 k            [4096][512]
    ushort* vbT   = kb16 + NE;                // bf16 v^T          [(b*8+h)*64+d][1024]
    ushort* ab    = vbT + NE;                 // bf16 attn out     [4096][512]
    ushort* wtQKV = ab + NE;                  // bf16 W^T concat   [1536][512]
    ushort* wt3   = wtQKV + (size_t)3 * DM * DM;
    ushort* bins  = wt3 + (size_t)DM * DM;    // u16 packed idx    [4][1024][1024]

    prep_kernel<<<3328, 256, 0, stream>>>(
        p, pcoords, wq_w, wk_w, wv_w, wo_w, pb, wtQKV, wt3, bins);

    gemm_qkv<<<dim3(24, NTOK / 128), 256, 0, stream>>>(
        pb, wtQKV, wq_b, wk_b, wv_b, qb16, kb16, vbT);

    attn_mfma<<<dim3(16, NH, BATCH), 256, 0, stream>>>(
        qb16, kb16, vbT, bins, rpe, ab);

    gemm_out<<<dim3(8, NTOK / 64), 256, 0, stream>>>(ab, wt3, wo_b, out);
}